// Round 1
// 1319.131 us; speedup vs baseline: 1.2021x; 1.2021x over previous
//
#include <hip/hip_runtime.h>
#include <stdint.h>

#define DD   128   // D
#define G2D  256   // 2*D
#define G4D  512   // 4*D
#define GPB  8     // graphs per block
#define SLOT 64    // LDS node-row slots per graph
#define ASTR 264   // padded stride (shorts) of A tile (bank-conflict pad)

typedef float  f32x4  __attribute__((ext_vector_type(4)));
typedef short  s16x4  __attribute__((ext_vector_type(4)));
typedef short  s16x8  __attribute__((ext_vector_type(8)));
typedef __bf16 bf16x8 __attribute__((ext_vector_type(8)));

__device__ __forceinline__ short f2bf(float f) {
  unsigned u = __builtin_bit_cast(unsigned, f);
  u += 0x7FFFu + ((u >> 16) & 1u);   // RNE
  return (short)(u >> 16);
}
__device__ __forceinline__ float bf2f(short s) {
  unsigned u = ((unsigned)(unsigned short)s) << 16;
  return __builtin_bit_cast(float, u);
}
__device__ __forceinline__ float sigmoidf_(float x) {
  return 1.f / (1.f + __expf(-x));
}
__device__ __forceinline__ float tanhf_(float x) {
  x = fminf(fmaxf(x, -15.f), 15.f);
  float e = __expf(2.f * x);
  return (e - 1.f) / (e + 1.f);
}

// seg[g] = lower_bound(ind, g) for g in [0..G]; graph_indicator is sorted.
__global__ void seg_kernel(const int* __restrict__ ind, int* __restrict__ seg,
                           int N, int G) {
  int g = blockIdx.x * blockDim.x + threadIdx.x;
  if (g > G) return;
  int lo = 0, hi = N;
  while (lo < hi) {
    int mid = (lo + hi) >> 1;
    if (ind[mid] < g) lo = mid + 1; else hi = mid;
  }
  seg[g] = lo;
}

// WT[n][k] = bf16(W[k][n]); W is [256,512] fp32, WT is [512,256] bf16
__global__ void wconv_kernel(const float* __restrict__ W, short* __restrict__ WT) {
  int idx = blockIdx.x * blockDim.x + threadIdx.x;  // 131072 threads
  int n = idx & (G4D - 1);
  int k = idx >> 9;
  WT[(size_t)n * G2D + k] = f2bf(W[(size_t)k * G4D + n]);
}

// Fully fused: 8 graphs per 512-thread block, all 8 steps in-kernel.
// nf staged once to LDS (bf16, 64-row slot/graph; overflow rows read fp32
// from global). carry/mem states in LDS. Per-wave W slice (32KB) cached in
// VGPRs once and reused all 7 LSTM steps. Output written directly.
__global__ void __launch_bounds__(512) fused_kernel(
    const float* __restrict__ nf, const int* __restrict__ seg,
    const short* __restrict__ WT, const float* __restrict__ bias,
    float* __restrict__ out, int G) {
  extern __shared__ char smem[];
  short* nfb   = (short*)smem;                              // [GPB][SLOT][DD] bf16
  short* A     = (short*)(smem + GPB * SLOT * DD * 2);      // [16][ASTR] bf16
  float* carry = (float*)(smem + GPB * SLOT * DD * 2 + 16 * ASTR * 2); // [GPB][DD]
  float* mem   = (float*)((char*)carry + GPB * DD * 4);     // [GPB][DD]

  const int t    = threadIdx.x;
  const int w    = t >> 6;         // wave id = local graph id (0..7)
  const int lane = t & 63;
  const int gq   = lane >> 4;      // group 0..3 (== MFMA quad)
  const int sl   = lane & 15;      // sub-lane (== MFMA l16)
  const int g0   = blockIdx.x * GPB;
  const int g    = g0 + w;
  const bool active = (g < G);

  // ---- init: zero A tile (incl. garbage rows 8..15) and mem state ----
  {
    int* az = (int*)A;
    for (int i = t; i < (16 * ASTR) / 2; i += 512) az[i] = 0;
    for (int i = t; i < GPB * DD; i += 512) mem[i] = 0.f;
  }
  int s0 = 0, n = 0;
  if (active) { s0 = seg[g]; n = seg[g + 1] - s0; }
  // carry row w: read only by wave w until the first epilogue -> no barrier needed
  carry[w * DD + lane]      = 0.f;
  carry[w * DD + 64 + lane] = 0.f;
  __syncthreads();   // A/mem zero visible before anyone writes/reads them

  // ---- stage this wave's graph rows (up to SLOT) into LDS, depth-2 pipeline ----
  short* slot = nfb + w * (SLOT * DD);
  const int nl = n < SLOT ? n : SLOT;
  {
    const int r2 = lane >> 5;          // row parity 0/1
    const int c  = lane & 31;          // f32x4 index within row
    const int iters = (nl + 1) >> 1;
    f32x4 vc; int rowc = r2; bool okc = rowc < nl;
    if (okc) vc = *((const f32x4*)(nf + (size_t)(s0 + rowc) * DD) + c);
    for (int i = 0; i < iters; ++i) {
      const int rown = (i + 1) * 2 + r2;
      f32x4 vn; const bool okn = rown < nl;
      if (okn) vn = *((const f32x4*)(nf + (size_t)(s0 + rown) * DD) + c);
      if (okc) {
        s16x4 o;
        o[0] = f2bf(vc.x); o[1] = f2bf(vc.y); o[2] = f2bf(vc.z); o[3] = f2bf(vc.w);
        *(s16x4*)(slot + (size_t)rowc * DD + c * 4) = o;
      }
      vc = vn; rowc = rown; okc = okn;
    }
  }

  // ---- cache this wave's W slice in registers: bw[kc][gate] (128 VGPRs) ----
  s16x8 bw[8][4];
  #pragma unroll
  for (int kc = 0; kc < 8; ++kc) {
    const int k0 = kc * 32 + gq * 8;
    #pragma unroll
    for (int gi = 0; gi < 4; ++gi) {
      const int ncol = gi * DD + w * 16 + sl;
      bw[kc][gi] = *(const s16x8*)(WT + (size_t)ncol * G2D + k0);
    }
  }
  // bias registers (per-lane constant across steps)
  const int colB = w * 16 + sl;
  const float bU = bias[0 * DD + colB], bF = bias[1 * DD + colB],
              bC = bias[2 * DD + colB], bO = bias[3 * DD + colB];

  #pragma unroll 1
  for (int step = 0; step < 8; ++step) {
    // ================= Phase A: attention readout (wave-local) =================
    float r[8];
    #pragma unroll
    for (int k = 0; k < 8; ++k) r[k] = 0.f;

    if (active && n > 0) {
      float m = -1e30f, l = 0.f;
      float acc[8];
      #pragma unroll
      for (int k = 0; k < 8; ++k) acc[k] = 0.f;

      if (step == 0) {
        // carry == 0 -> all scores exactly 0 -> uniform softmax == mean pool
        const int nfull = nl >> 2, rem = nl & 3;
        #pragma unroll 2
        for (int i = 0; i < nfull; ++i) {
          s16x8 xr = *(const s16x8*)(slot + (size_t)(i * 4 + gq) * DD + sl * 8);
          #pragma unroll
          for (int k = 0; k < 8; ++k) acc[k] += bf2f(xr[k]);
          l += 1.f;
        }
        if (gq < rem) {
          s16x8 xr = *(const s16x8*)(slot + (size_t)(nfull * 4 + gq) * DD + sl * 8);
          #pragma unroll
          for (int k = 0; k < 8; ++k) acc[k] += bf2f(xr[k]);
          l += 1.f;
        }
        for (int j = SLOT + gq; j < n; j += 4) {   // overflow rows (rare)
          const f32x4* gp = (const f32x4*)(nf + (size_t)(s0 + j) * DD) + sl * 2;
          const f32x4 a = gp[0], b = gp[1];
          const float xf[8] = {a.x, a.y, a.z, a.w, b.x, b.y, b.z, b.w};
          #pragma unroll
          for (int k = 0; k < 8; ++k) acc[k] += xf[k];
          l += 1.f;
        }
        m = 0.f;
      } else {
        const f32x4 c0 = *(const f32x4*)(carry + w * DD + sl * 8);
        const f32x4 c1 = *(const f32x4*)(carry + w * DD + sl * 8 + 4);
        auto upd = [&](const float xf[8]) {
          float s = xf[0] * c0.x + xf[1] * c0.y + xf[2] * c0.z + xf[3] * c0.w
                  + xf[4] * c1.x + xf[5] * c1.y + xf[6] * c1.z + xf[7] * c1.w;
          #pragma unroll
          for (int off = 1; off < 16; off <<= 1) s += __shfl_xor(s, off, 64);
          const float nm = fmaxf(m, s);
          const float sc = __expf(m - nm);   // exp(-huge)=0 on first iter
          const float p  = __expf(s - nm);
          l = l * sc + p;
          #pragma unroll
          for (int k = 0; k < 8; ++k) acc[k] = acc[k] * sc + p * xf[k];
          m = nm;
        };
        const int nfull = nl >> 2, rem = nl & 3;
        #pragma unroll 2
        for (int i = 0; i < nfull; ++i) {
          s16x8 xr = *(const s16x8*)(slot + (size_t)(i * 4 + gq) * DD + sl * 8);
          float xf[8];
          #pragma unroll
          for (int k = 0; k < 8; ++k) xf[k] = bf2f(xr[k]);
          upd(xf);
        }
        if (gq < rem) {
          s16x8 xr = *(const s16x8*)(slot + (size_t)(nfull * 4 + gq) * DD + sl * 8);
          float xf[8];
          #pragma unroll
          for (int k = 0; k < 8; ++k) xf[k] = bf2f(xr[k]);
          upd(xf);
        }
        for (int j = SLOT + gq; j < n; j += 4) {   // overflow rows (rare)
          const f32x4* gp = (const f32x4*)(nf + (size_t)(s0 + j) * DD) + sl * 2;
          const f32x4 a = gp[0], b = gp[1];
          const float xf[8] = {a.x, a.y, a.z, a.w, b.x, b.y, b.z, b.w};
          upd(xf);
        }
      }
      // merge the 4 group states (xor 16, then xor 32)
      #pragma unroll
      for (int ww = 16; ww <= 32; ww <<= 1) {
        const float m2 = __shfl_xor(m, ww, 64);
        const float l2 = __shfl_xor(l, ww, 64);
        const float M  = fmaxf(m, m2);
        const float e1 = __expf(m - M);
        const float e2 = __expf(m2 - M);
        l = l * e1 + l2 * e2;
        #pragma unroll
        for (int k = 0; k < 8; ++k) {
          const float a2 = __shfl_xor(acc[k], ww, 64);
          acc[k] = acc[k] * e1 + a2 * e2;
        }
        m = M;
      }
      if (gq == 0) {
        const float inv = (l > 0.f) ? 1.f / l : 0.f;
        s16x8 pk;
        #pragma unroll
        for (int k = 0; k < 8; ++k) { r[k] = acc[k] * inv; pk[k] = f2bf(r[k]); }
        *(s16x8*)(A + w * ASTR + DD + sl * 8) = pk;   // readout half of A (bf16)
      }
    }

    if (step == 7) {            // output = [carry_after_step6 | readout_step7]
      if (active) {
        if (gq == 0) {
          f32x4 r0 = {r[0], r[1], r[2], r[3]};
          f32x4 r1 = {r[4], r[5], r[6], r[7]};
          *(f32x4*)(out + (size_t)g * G2D + DD + sl * 8)     = r0;
          *(f32x4*)(out + (size_t)g * G2D + DD + sl * 8 + 4) = r1;
        } else if (gq == 1) {
          const f32x4 a = *(const f32x4*)(carry + w * DD + sl * 8);
          const f32x4 b = *(const f32x4*)(carry + w * DD + sl * 8 + 4);
          *(f32x4*)(out + (size_t)g * G2D + sl * 8)     = a;
          *(f32x4*)(out + (size_t)g * G2D + sl * 8 + 4) = b;
        }
      }
      break;                    // uniform across block
    }
    __syncthreads();            // A readout visible; carry reads done

    // ================= Phase B: batched LSTM via MFMA =================
    // wave w owns cols w*16..w*16+15 of each of the 4 gates; W from registers.
    f32x4 az[4];
    #pragma unroll
    for (int gi = 0; gi < 4; ++gi) az[gi] = (f32x4){0.f, 0.f, 0.f, 0.f};
    #pragma unroll
    for (int kc = 0; kc < 8; ++kc) {
      const int k0 = kc * 32 + gq * 8;
      const s16x8 af = *(const s16x8*)(A + (size_t)sl * ASTR + k0);
      #pragma unroll
      for (int gi = 0; gi < 4; ++gi)
        az[gi] = __builtin_amdgcn_mfma_f32_16x16x32_bf16(
            __builtin_bit_cast(bf16x8, af), __builtin_bit_cast(bf16x8, bw[kc][gi]),
            az[gi], 0, 0, 0);
    }
    __syncthreads();            // all A reads complete before epilogue rewrites A
    // epilogue: C/D layout col=lane&15, row=quad*4+reg; rows 0..7 = our graphs
    if (gq < 2) {
      #pragma unroll
      for (int rr = 0; rr < 4; ++rr) {
        const int gg = gq * 4 + rr;      // local graph 0..7
        if (g0 + gg < G) {
          const float u = az[0][rr] + bU;
          const float f = az[1][rr] + bF;
          const float c = az[2][rr] + bC;
          const float o = az[3][rr] + bO;
          const float mo = mem[gg * DD + colB];
          const float mn = sigmoidf_(f) * mo + sigmoidf_(u) * tanhf_(c);
          mem[gg * DD + colB] = mn;
          const float cn = sigmoidf_(o) * tanhf_(mn);
          carry[gg * DD + colB] = cn;      // f32 state for next score pass
          A[gg * ASTR + colB] = f2bf(cn);  // bf16 carry half of next A
        }
      }
    }
    __syncthreads();            // epilogue visible before next phase A / B
  }
}

extern "C" void kernel_launch(void* const* d_in, const int* in_sizes, int n_in,
                              void* d_out, int out_size, void* d_ws, size_t ws_size,
                              hipStream_t stream) {
  const float* nf   = (const float*)d_in[0];
  const int*   ind  = (const int*)d_in[1];
  const float* W    = (const float*)d_in[2];
  const float* bias = (const float*)d_in[3];
  int N = in_sizes[1];
  int G = out_size / G2D;   // 25000

  char* ws = (char*)d_ws;
  short* WT  = (short*)ws;                       // 512*256*2 = 262144 B
  int*   seg = (int*)(ws + 262144);              // (G+1)*4 B
  (void)ws_size; (void)n_in;

  seg_kernel<<<(G + 256) / 256, 256, 0, stream>>>(ind, seg, N, G);
  wconv_kernel<<<(G2D * G4D) / 256, 256, 0, stream>>>(W, WT);

  const int SMEM_BYTES = GPB * SLOT * DD * 2     // 131072  nf tile
                       + 16 * ASTR * 2           //   8448  A tile (padded)
                       + GPB * DD * 4            //   4096  carry
                       + GPB * DD * 4;           //   4096  mem   => 147712
  static bool attr_set = false;
  if (!attr_set) {
    hipFuncSetAttribute(reinterpret_cast<const void*>(fused_kernel),
                        hipFuncAttributeMaxDynamicSharedMemorySize, SMEM_BYTES);
    attr_set = true;
  }
  fused_kernel<<<(G + GPB - 1) / GPB, 512, SMEM_BYTES, stream>>>(
      nf, seg, WT, bias, (float*)d_out, G);
}